// Round 1
// baseline (219.645 us; speedup 1.0000x reference)
//
#include <hip/hip_runtime.h>

// Problem: B=4,S=4096,D=1024,H=16,HID=ATT=64
//   qkv = x @ [Wq|Wk|Wv] + bias       (16384 x 1024) @ (1024 x 3072)
//   per token: scores(16x16) = q k^T / 8 over HID=64; softmax over heads; ctx = P V
// Strategy: bf16 MFMA GEMM (m97 128^2 structure) -> bf16 qkv in ws -> per-token wave attention.

#define AS1 __attribute__((address_space(1)))
#define AS3 __attribute__((address_space(3)))

typedef __bf16 bf16x8 __attribute__((ext_vector_type(8)));
typedef float f32x4 __attribute__((ext_vector_type(4)));
typedef unsigned short u16x8 __attribute__((ext_vector_type(8)));

static constexpr int MTOK = 16384;   // B*S tokens
static constexpr int N3   = 3072;    // 3*H*HID
static constexpr int KD   = 1024;    // D

__device__ __forceinline__ unsigned short f2bf(float f) {
  unsigned u = __float_as_uint(f);
  unsigned r = u + 0x7FFFu + ((u >> 16) & 1u);   // round-to-nearest-even
  return (unsigned short)(r >> 16);
}
__device__ __forceinline__ float bf2f(unsigned short s) {
  return __uint_as_float(((unsigned)s) << 16);
}

__device__ __forceinline__ void gload_lds16(const void* g, void* lds_uniform) {
  __builtin_amdgcn_global_load_lds((const AS1 void*)g, (AS3 void*)lds_uniform, 16, 0, 0);
}

// ---------------- kernel 1: x f32 -> bf16 ----------------
__global__ __launch_bounds__(256) void cvt_x_kernel(const float* __restrict__ x,
                                                    unsigned short* __restrict__ xb) {
  int i = blockIdx.x * 256 + threadIdx.x;      // 8 elements per thread, exact grid
  const float4* p = (const float4*)x;
  float4 a = p[2 * i], b = p[2 * i + 1];
  u16x8 o;
  o[0] = f2bf(a.x); o[1] = f2bf(a.y); o[2] = f2bf(a.z); o[3] = f2bf(a.w);
  o[4] = f2bf(b.x); o[5] = f2bf(b.y); o[6] = f2bf(b.z); o[7] = f2bf(b.w);
  *((u16x8*)xb + i) = o;
}

// ------- kernel 2: W (K x N, f32) -> WT (N x K, bf16), bias concat -------
__global__ __launch_bounds__(256) void prep_w_kernel(const float* __restrict__ Wq,
                                                     const float* __restrict__ Wk,
                                                     const float* __restrict__ Wv,
                                                     const float* __restrict__ bq,
                                                     const float* __restrict__ bk,
                                                     const float* __restrict__ bv,
                                                     unsigned short* __restrict__ WT,
                                                     float* __restrict__ bcat) {
  __shared__ float tile[32][33];
  int kt = blockIdx.x * 32;          // k tile (0..1023)
  int nt = blockIdx.y * 32;          // global n tile (0..3071)
  const float* W; const float* bias; int nb;
  if (nt < 1024)      { W = Wq; bias = bq; nb = nt; }
  else if (nt < 2048) { W = Wk; bias = bk; nb = nt - 1024; }
  else                { W = Wv; bias = bv; nb = nt - 2048; }
  int tx = threadIdx.x & 31, ty = threadIdx.x >> 5;  // ty 0..7
#pragma unroll
  for (int it = 0; it < 4; ++it) {
    int kk = it * 8 + ty;
    tile[kk][tx] = W[(size_t)(kt + kk) * 1024 + nb + tx];
  }
  __syncthreads();
#pragma unroll
  for (int it = 0; it < 4; ++it) {
    int nn = it * 8 + ty;
    WT[(size_t)(nt + nn) * 1024 + kt + tx] = f2bf(tile[tx][nn]);
  }
  if (blockIdx.x == 0 && threadIdx.x < 32)
    bcat[nt + threadIdx.x] = bias[nb + threadIdx.x];
}

// ---------------- kernel 3: GEMM qkv = xb @ WT^T + bias (bf16 out) ----------------
// 128x128 tile, BK=64, 256 threads = 4 waves in 2x2, 16x16x32 bf16 MFMA.
__global__ __launch_bounds__(256) void gemm_qkv_kernel(const unsigned short* __restrict__ A,
                                                       const unsigned short* __restrict__ Bt,
                                                       const float* __restrict__ bias,
                                                       unsigned short* __restrict__ C) {
  __shared__ __align__(16) unsigned short As[128 * 64];
  __shared__ __align__(16) unsigned short Bs[128 * 64];
  const int tid = threadIdx.x;
  const int lane = tid & 63;
  const int wave = tid >> 6;
  const int wm = wave >> 1, wn = wave & 1;       // 2x2 wave grid, 64x64 each
  const int m0 = blockIdx.x * 128;
  const int n0 = blockIdx.y * 128;
  const int chunk = lane >> 4;                   // 0..3  (k-subchunk of 8)
  const int hl = lane & 15;                      // fragment row/col
  f32x4 acc[4][4] = {};

  for (int kt = 0; kt < KD; kt += 64) {
#pragma unroll
    for (int it = 0; it < 4; ++it) {
      int j = it * 256 + tid;                    // 0..1023 : row=j>>3, 16B chunk=j&7
      int row = j >> 3, c8 = (j & 7) * 8;
      int ldsoff = (it * 256 + (tid & 0xC0)) * 8;  // wave-uniform base (elements)
      gload_lds16(A  + (size_t)(m0 + row) * KD + kt + c8, As + ldsoff);
      gload_lds16(Bt + (size_t)(n0 + row) * KD + kt + c8, Bs + ldsoff);
    }
    __syncthreads();
#pragma unroll
    for (int ks = 0; ks < 2; ++ks) {
      bf16x8 af[4], bfr[4];
#pragma unroll
      for (int m = 0; m < 4; ++m) {
        int row = wm * 64 + m * 16 + hl;
        af[m] = *(const bf16x8*)&As[row * 64 + ks * 32 + chunk * 8];
      }
#pragma unroll
      for (int n = 0; n < 4; ++n) {
        int col = wn * 64 + n * 16 + hl;
        bfr[n] = *(const bf16x8*)&Bs[col * 64 + ks * 32 + chunk * 8];
      }
#pragma unroll
      for (int m = 0; m < 4; ++m)
#pragma unroll
        for (int n = 0; n < 4; ++n)
          acc[m][n] = __builtin_amdgcn_mfma_f32_16x16x32_bf16(af[m], bfr[n], acc[m][n], 0, 0, 0);
    }
    __syncthreads();
  }

  // epilogue: C row=(lane>>4)*4+r, col=lane&15 within each 16x16 fragment
#pragma unroll
  for (int n = 0; n < 4; ++n) {
    int col = n0 + wn * 64 + n * 16 + hl;
    float bv = bias[col];
#pragma unroll
    for (int m = 0; m < 4; ++m) {
      int rowb = m0 + wm * 64 + m * 16 + chunk * 4;
#pragma unroll
      for (int r = 0; r < 4; ++r) {
        float v = acc[m][n][r] + bv;
        C[(size_t)(rowb + r) * N3 + col] = f2bf(v);
      }
    }
  }
}

// ---------------- kernel 4: per-token head attention ----------------
// 1 wave per token; scores via 2 MFMAs straight from global; softmax across 16-lane
// groups; P -> LDS; PV on VALU; coalesced f32 out.
__global__ __launch_bounds__(256) void attn_kernel(const unsigned short* __restrict__ qkv,
                                                   float* __restrict__ out) {
  __shared__ float p_lds[4][16][17];
  const int tid = threadIdx.x;
  const int lane = tid & 63;
  const int w = tid >> 6;
  const size_t token = (size_t)blockIdx.x * 4 + w;
  const unsigned short* rowp = qkv + token * N3;
  const int head = lane & 15;     // A-frag row (q head) and B-frag col (k head)
  const int chunk = lane >> 4;    // k-dim subchunk

  const int o = head * 64 + chunk * 8;
  bf16x8 q0 = *(const bf16x8*)(rowp + o);
  bf16x8 q1 = *(const bf16x8*)(rowp + o + 32);
  bf16x8 k0 = *(const bf16x8*)(rowp + 1024 + o);
  bf16x8 k1 = *(const bf16x8*)(rowp + 1024 + o + 32);
  f32x4 c = {0.f, 0.f, 0.f, 0.f};
  c = __builtin_amdgcn_mfma_f32_16x16x32_bf16(q0, k0, c, 0, 0, 0);
  c = __builtin_amdgcn_mfma_f32_16x16x32_bf16(q1, k1, c, 0, 0, 0);
  // c[r] = scores[row = chunk*4+r][col = head]

#pragma unroll
  for (int r = 0; r < 4; ++r) {
    float s = c[r] * 0.125f;
    float m = s;
#pragma unroll
    for (int off = 1; off < 16; off <<= 1) m = fmaxf(m, __shfl_xor(m, off, 64));
    float e = __expf(s - m);
    float sum = e;
#pragma unroll
    for (int off = 1; off < 16; off <<= 1) sum += __shfl_xor(sum, off, 64);
    p_lds[w][chunk * 4 + r][head] = e / sum;
  }
  __syncthreads();

  // PV: lane owns (i = lane>>2, a-block = lane&3): 16 f32 outputs
  const int i = lane >> 2;
  const int ab = lane & 3;
  const unsigned short* vbase = rowp + 2048 + ab * 16;
  float accv[16];
#pragma unroll
  for (int cc = 0; cc < 16; ++cc) accv[cc] = 0.f;
#pragma unroll
  for (int j = 0; j < 16; ++j) {
    float pij = p_lds[w][i][j];
    u16x8 v0 = *(const u16x8*)(vbase + j * 64);
    u16x8 v1 = *(const u16x8*)(vbase + j * 64 + 8);
#pragma unroll
    for (int cc = 0; cc < 8; ++cc) accv[cc] += pij * bf2f(v0[cc]);
#pragma unroll
    for (int cc = 0; cc < 8; ++cc) accv[8 + cc] += pij * bf2f(v1[cc]);
  }
  float* op = out + token * 1024 + i * 64 + ab * 16;
#pragma unroll
  for (int cc = 0; cc < 16; cc += 4) {
    f32x4 v = {accv[cc], accv[cc + 1], accv[cc + 2], accv[cc + 3]};
    *(f32x4*)(op + cc) = v;
  }
}

extern "C" void kernel_launch(void* const* d_in, const int* in_sizes, int n_in,
                              void* d_out, int out_size, void* d_ws, size_t ws_size,
                              hipStream_t stream) {
  const float* x  = (const float*)d_in[0];
  const float* Wq = (const float*)d_in[1];
  const float* bq = (const float*)d_in[2];
  const float* Wk = (const float*)d_in[3];
  const float* bk = (const float*)d_in[4];
  const float* Wv = (const float*)d_in[5];
  const float* bv = (const float*)d_in[6];
  float* out = (float*)d_out;

  char* ws = (char*)d_ws;
  unsigned short* xb   = (unsigned short*)ws;               // 16384*1024*2 = 33,554,432
  unsigned short* WT   = (unsigned short*)(ws + 33554432);  //  3072*1024*2 =  6,291,456
  float*          bcat = (float*)(ws + 39845888);           //  3072*4      =     12,288
  unsigned short* qkv  = (unsigned short*)(ws + 39858176);  // 16384*3072*2 = 100,663,296

  cvt_x_kernel<<<dim3((MTOK * KD / 8) / 256), 256, 0, stream>>>(x, xb);
  prep_w_kernel<<<dim3(32, 96), 256, 0, stream>>>(Wq, Wk, Wv, bq, bk, bv, WT, bcat);
  gemm_qkv_kernel<<<dim3(MTOK / 128, N3 / 128), 256, 0, stream>>>(xb, WT, bcat, qkv);
  attn_kernel<<<dim3(MTOK / 4), 256, 0, stream>>>(qkv, out);
}

// Round 2
// 178.366 us; speedup vs baseline: 1.2314x; 1.2314x over previous
//
#include <hip/hip_runtime.h>

// Problem: B=4,S=4096,D=1024,H=16,HID=ATT=64
//   qkv = x @ [Wq|Wk|Wv] + bias       (16384 x 1024) @ (1024 x 3072)
//   per token: scores(16x16) = q k^T / 8 over HID=64; softmax over heads; ctx = P V
// R2: GEMM rewritten as 256x256 tile, BK=32, 4-deep LDS ring with counted vmcnt(12),
//     raw s_barrier (no drain), XOR-swizzled LDS (T2, both-sides: pre-swizzled global
//     source + swizzled ds_read, linear global_load_lds dest).

#define AS1 __attribute__((address_space(1)))
#define AS3 __attribute__((address_space(3)))

typedef __bf16 bf16x8 __attribute__((ext_vector_type(8)));
typedef float f32x4 __attribute__((ext_vector_type(4)));
typedef unsigned short u16x8 __attribute__((ext_vector_type(8)));

static constexpr int MTOK = 16384;   // B*S tokens
static constexpr int N3   = 3072;    // 3*H*HID
static constexpr int KD   = 1024;    // D
static constexpr int BK   = 32;      // K-step
static constexpr int NT   = KD / BK; // 32 K-steps

__device__ __forceinline__ unsigned short f2bf(float f) {
  unsigned u = __float_as_uint(f);
  unsigned r = u + 0x7FFFu + ((u >> 16) & 1u);   // round-to-nearest-even
  return (unsigned short)(r >> 16);
}
__device__ __forceinline__ float bf2f(unsigned short s) {
  return __uint_as_float(((unsigned)s) << 16);
}

__device__ __forceinline__ void gload_lds16(const void* g, void* lds_uniform) {
  __builtin_amdgcn_global_load_lds((const AS1 void*)g, (AS3 void*)lds_uniform, 16, 0, 0);
}

// ---------------- kernel 1: x f32 -> bf16 ----------------
__global__ __launch_bounds__(256) void cvt_x_kernel(const float* __restrict__ x,
                                                    unsigned short* __restrict__ xb) {
  int i = blockIdx.x * 256 + threadIdx.x;      // 8 elements per thread, exact grid
  const float4* p = (const float4*)x;
  float4 a = p[2 * i], b = p[2 * i + 1];
  u16x8 o;
  o[0] = f2bf(a.x); o[1] = f2bf(a.y); o[2] = f2bf(a.z); o[3] = f2bf(a.w);
  o[4] = f2bf(b.x); o[5] = f2bf(b.y); o[6] = f2bf(b.z); o[7] = f2bf(b.w);
  *((u16x8*)xb + i) = o;
}

// ------- kernel 2: W (K x N, f32) -> WT (N x K, bf16), bias concat -------
__global__ __launch_bounds__(256) void prep_w_kernel(const float* __restrict__ Wq,
                                                     const float* __restrict__ Wk,
                                                     const float* __restrict__ Wv,
                                                     const float* __restrict__ bq,
                                                     const float* __restrict__ bk,
                                                     const float* __restrict__ bv,
                                                     unsigned short* __restrict__ WT,
                                                     float* __restrict__ bcat) {
  __shared__ float tile[32][33];
  int kt = blockIdx.x * 32;          // k tile (0..1023)
  int nt = blockIdx.y * 32;          // global n tile (0..3071)
  const float* W; const float* bias; int nb;
  if (nt < 1024)      { W = Wq; bias = bq; nb = nt; }
  else if (nt < 2048) { W = Wk; bias = bk; nb = nt - 1024; }
  else                { W = Wv; bias = bv; nb = nt - 2048; }
  int tx = threadIdx.x & 31, ty = threadIdx.x >> 5;  // ty 0..7
#pragma unroll
  for (int it = 0; it < 4; ++it) {
    int kk = it * 8 + ty;
    tile[kk][tx] = W[(size_t)(kt + kk) * 1024 + nb + tx];
  }
  __syncthreads();
#pragma unroll
  for (int it = 0; it < 4; ++it) {
    int nn = it * 8 + ty;
    WT[(size_t)(nt + nn) * 1024 + kt + tx] = f2bf(tile[tx][nn]);
  }
  if (blockIdx.x == 0 && threadIdx.x < 32)
    bcat[nt + threadIdx.x] = bias[nb + threadIdx.x];
}

// ---------------- kernel 3: GEMM qkv = xb @ WT^T + bias (bf16 out) ----------------
// 256x256 tile, BK=32, 512 threads = 8 waves (2M x 4N), per-wave C = 128x64.
// LDS ring: 4 buffers x (A[256][32] + B[256][32]) bf16 = 128 KiB.
// Swizzle: logical 16B-slot s of row r lives at phys slot s ^ ((r>>1)&3).
//   - global_load_lds dest stays linear (rule #21); the SOURCE k-offset is
//     pre-permuted with the same involution; ds_read applies the XOR on its addr.
//   - read conflict: quarter-wave (16 lanes) covers all 8 16B-positions/128B twice
//     -> 2-way = free.
__global__ __launch_bounds__(512, 2) void gemm_qkv_kernel(const unsigned short* __restrict__ A,
                                                          const unsigned short* __restrict__ Bt,
                                                          const float* __restrict__ bias,
                                                          unsigned short* __restrict__ C) {
  __shared__ __align__(16) unsigned short lds[4][16384];  // [buf][A:8192 | B:8192]
  const int tid  = threadIdx.x;
  const int lane = tid & 63;
  const int wave = tid >> 6;
  const int wm = wave >> 2, wn = wave & 3;   // 2x4 wave grid
  const int m0 = blockIdx.x * 256;
  const int n0 = blockIdx.y * 256;
  const int chunk = lane >> 4;               // logical 16B slot (k-chunk of 8)
  const int hl = lane & 15;                  // fragment row/col within 16x16

  // --- staging geometry: 4 gload_lds16 per thread per tile ---
  const int srow = tid >> 2;                 // 0..127
  const int sp   = tid & 3;                  // phys slot being written
  const int gc_lo = (sp ^ ((srow >> 1) & 3)) * 8;       // pre-swizzled global k-offset
  // (row+128)>>1 & 3 == row>>1 & 3 for row<128, since 128>>1=64 ≡ 0 mod 4
  const size_t arow0 = (size_t)(m0 + srow) * KD;
  const size_t arow1 = (size_t)(m0 + 128 + srow) * KD;
  const size_t brow0 = (size_t)(n0 + srow) * KD;
  const size_t brow1 = (size_t)(n0 + 128 + srow) * KD;
  const int ubase = wave * 512;              // wave-uniform LDS base (elements)

  // --- fragment read offsets (elements within a buffer), precomputed ---
  int aoff[8], boff[4];
#pragma unroll
  for (int m = 0; m < 8; ++m) {
    int row = wm * 128 + m * 16 + hl;
    aoff[m] = row * 32 + (chunk ^ ((row >> 1) & 3)) * 8;
  }
#pragma unroll
  for (int n = 0; n < 4; ++n) {
    int row = wn * 64 + n * 16 + hl;
    boff[n] = 8192 + row * 32 + (chunk ^ ((row >> 1) & 3)) * 8;
  }

  f32x4 acc[8][4] = {};

#define STAGE(T)                                                                 \
  do {                                                                           \
    unsigned short* buf = lds[(T) & 3];                                          \
    int kt = (T) * BK;                                                           \
    gload_lds16(A  + arow0 + kt + gc_lo, buf + ubase);                           \
    gload_lds16(A  + arow1 + kt + gc_lo, buf + 4096 + ubase);                    \
    gload_lds16(Bt + brow0 + kt + gc_lo, buf + 8192 + ubase);                    \
    gload_lds16(Bt + brow1 + kt + gc_lo, buf + 12288 + ubase);                   \
  } while (0)

#define COMPUTE(T)                                                               \
  do {                                                                           \
    const unsigned short* buf = lds[(T) & 3];                                    \
    bf16x8 af[8], bfr[4];                                                        \
    _Pragma("unroll") for (int m = 0; m < 8; ++m)                                \
      af[m] = *(const bf16x8*)&buf[aoff[m]];                                     \
    _Pragma("unroll") for (int n = 0; n < 4; ++n)                                \
      bfr[n] = *(const bf16x8*)&buf[boff[n]];                                    \
    _Pragma("unroll") for (int m = 0; m < 8; ++m)                                \
      _Pragma("unroll") for (int n = 0; n < 4; ++n)                              \
        acc[m][n] = __builtin_amdgcn_mfma_f32_16x16x32_bf16(af[m], bfr[n],       \
                                                            acc[m][n], 0, 0, 0); \
  } while (0)

  // prologue: fill 3 ring slots
  STAGE(0); STAGE(1); STAGE(2);

  // main loop: stage t+3, wait own tile-t loads (12 newer stay in flight), barrier
  // (=> ALL waves' tile-t loads landed), compute, barrier (frees buf[t&3] for t+1's stage).
  for (int t = 0; t < NT - 3; ++t) {
    STAGE(t + 3);
    asm volatile("s_waitcnt vmcnt(12)\n\ts_barrier" ::: "memory");
    COMPUTE(t);
    asm volatile("s_barrier" ::: "memory");
  }
  asm volatile("s_waitcnt vmcnt(8)\n\ts_barrier" ::: "memory");
  COMPUTE(NT - 3);
  asm volatile("s_barrier" ::: "memory");
  asm volatile("s_waitcnt vmcnt(4)\n\ts_barrier" ::: "memory");
  COMPUTE(NT - 2);
  asm volatile("s_barrier" ::: "memory");
  asm volatile("s_waitcnt vmcnt(0)\n\ts_barrier" ::: "memory");
  COMPUTE(NT - 1);
#undef STAGE
#undef COMPUTE

  // epilogue: fragment (m,n): C row = m0+wm*128+m*16+chunk*4+r, col = n0+wn*64+n*16+hl
#pragma unroll
  for (int n = 0; n < 4; ++n) {
    int col = n0 + wn * 64 + n * 16 + hl;
    float bv = bias[col];
#pragma unroll
    for (int m = 0; m < 8; ++m) {
      int rowb = m0 + wm * 128 + m * 16 + chunk * 4;
#pragma unroll
      for (int r = 0; r < 4; ++r) {
        float v = acc[m][n][r] + bv;
        C[(size_t)(rowb + r) * N3 + col] = f2bf(v);
      }
    }
  }
}

// ---------------- kernel 4: per-token head attention ----------------
// 1 wave per token; scores via 2 MFMAs straight from global; softmax across 16-lane
// groups; P -> LDS; PV on VALU; coalesced f32 out.
__global__ __launch_bounds__(256) void attn_kernel(const unsigned short* __restrict__ qkv,
                                                   float* __restrict__ out) {
  __shared__ float p_lds[4][16][17];
  const int tid = threadIdx.x;
  const int lane = tid & 63;
  const int w = tid >> 6;
  const size_t token = (size_t)blockIdx.x * 4 + w;
  const unsigned short* rowp = qkv + token * N3;
  const int head = lane & 15;     // A-frag row (q head) and B-frag col (k head)
  const int chunk = lane >> 4;    // k-dim subchunk

  const int o = head * 64 + chunk * 8;
  bf16x8 q0 = *(const bf16x8*)(rowp + o);
  bf16x8 q1 = *(const bf16x8*)(rowp + o + 32);
  bf16x8 k0 = *(const bf16x8*)(rowp + 1024 + o);
  bf16x8 k1 = *(const bf16x8*)(rowp + 1024 + o + 32);
  f32x4 c = {0.f, 0.f, 0.f, 0.f};
  c = __builtin_amdgcn_mfma_f32_16x16x32_bf16(q0, k0, c, 0, 0, 0);
  c = __builtin_amdgcn_mfma_f32_16x16x32_bf16(q1, k1, c, 0, 0, 0);
  // c[r] = scores[row = chunk*4+r][col = head]

#pragma unroll
  for (int r = 0; r < 4; ++r) {
    float s = c[r] * 0.125f;
    float m = s;
#pragma unroll
    for (int off = 1; off < 16; off <<= 1) m = fmaxf(m, __shfl_xor(m, off, 64));
    float e = __expf(s - m);
    float sum = e;
#pragma unroll
    for (int off = 1; off < 16; off <<= 1) sum += __shfl_xor(sum, off, 64);
    p_lds[w][chunk * 4 + r][head] = e / sum;
  }
  __syncthreads();

  // PV: lane owns (i = lane>>2, a-block = lane&3): 16 f32 outputs
  const int i = lane >> 2;
  const int ab = lane & 3;
  const unsigned short* vbase = rowp + 2048 + ab * 16;
  float accv[16];
#pragma unroll
  for (int cc = 0; cc < 16; ++cc) accv[cc] = 0.f;
#pragma unroll
  for (int j = 0; j < 16; ++j) {
    float pij = p_lds[w][i][j];
    u16x8 v0 = *(const u16x8*)(vbase + j * 64);
    u16x8 v1 = *(const u16x8*)(vbase + j * 64 + 8);
#pragma unroll
    for (int cc = 0; cc < 8; ++cc) accv[cc] += pij * bf2f(v0[cc]);
#pragma unroll
    for (int cc = 0; cc < 8; ++cc) accv[8 + cc] += pij * bf2f(v1[cc]);
  }
  float* op = out + token * 1024 + i * 64 + ab * 16;
#pragma unroll
  for (int cc = 0; cc < 16; cc += 4) {
    f32x4 v = {accv[cc], accv[cc + 1], accv[cc + 2], accv[cc + 3]};
    *(f32x4*)(op + cc) = v;
  }
}

extern "C" void kernel_launch(void* const* d_in, const int* in_sizes, int n_in,
                              void* d_out, int out_size, void* d_ws, size_t ws_size,
                              hipStream_t stream) {
  const float* x  = (const float*)d_in[0];
  const float* Wq = (const float*)d_in[1];
  const float* bq = (const float*)d_in[2];
  const float* Wk = (const float*)d_in[3];
  const float* bk = (const float*)d_in[4];
  const float* Wv = (const float*)d_in[5];
  const float* bv = (const float*)d_in[6];
  float* out = (float*)d_out;

  char* ws = (char*)d_ws;
  unsigned short* xb   = (unsigned short*)ws;               // 16384*1024*2 = 33,554,432
  unsigned short* WT   = (unsigned short*)(ws + 33554432);  //  3072*1024*2 =  6,291,456
  float*          bcat = (float*)(ws + 39845888);           //  3072*4      =     12,288
  unsigned short* qkv  = (unsigned short*)(ws + 39858176);  // 16384*3072*2 = 100,663,296

  cvt_x_kernel<<<dim3((MTOK * KD / 8) / 256), 256, 0, stream>>>(x, xb);
  prep_w_kernel<<<dim3(32, 96), 256, 0, stream>>>(Wq, Wk, Wv, bq, bk, bv, WT, bcat);
  gemm_qkv_kernel<<<dim3(MTOK / 256, N3 / 256), 512, 0, stream>>>(xb, WT, bcat, qkv);
  attn_kernel<<<dim3(MTOK / 4), 256, 0, stream>>>(qkv, out);
}